// Round 1
// baseline (255.799 us; speedup 1.0000x reference)
//
#include <hip/hip_runtime.h>

// SSIM (win=7, valid) fused single-pass kernel for (32,3,512,512) fp32 inputs.
// 96 planes of 512x512 -> mean over 96x506x506 S map.
//
// R3: wave-autonomous strips, ZERO barriers in the hot loop.
//   - Each WAVE owns one (img, strip): 23 output rows x full 512-col width.
//   - Lane l owns 8 contiguous columns [8l, 8l+8): vertical running sums V[5][8]
//     in registers; horizontal 7-sums via in-lane prefix + 6 __shfl_down halo
//     values from lane l+1 per quantity. No LDS exchange, no __syncthreads,
//     no lockstep between waves -> latency fully hideable.
//   - Per-block partial sums written to workspace; finalize kernel reduces
//     (no global atomic contention, no memset launch).

namespace {
constexpr int W       = 512;
constexpr int HH      = 512;
constexpr int NIMG    = 96;
constexpr int OW      = 506;
constexpr int RSTRIP  = 23;               // 22 strips * 23 rows = 506 output rows
constexpr int NSTRIP  = 22;
constexpr int WAVES   = NIMG * NSTRIP;    // 2112
constexpr int BLOCKS  = WAVES / 4;        // 528 blocks x 4 waves
constexpr float C1f   = 1.0e-4f;          // (0.01*1.0)^2
constexpr float C2f   = 9.0e-4f;          // (0.03*1.0)^2
constexpr float COVN  = 49.0f / 48.0f;    // NP/(NP-1)
constexpr float INV49 = 1.0f / 49.0f;
constexpr double NPIX = 96.0 * 506.0 * 506.0;   // 24,579,456
}

__device__ __forceinline__ void load8(const float* __restrict__ p, float v[8])
{
    float4 a = *(const float4*)(p);
    float4 b = *(const float4*)(p + 4);
    v[0] = a.x; v[1] = a.y; v[2] = a.z; v[3] = a.w;
    v[4] = b.x; v[5] = b.y; v[6] = b.z; v[7] = b.w;
}

__global__ __launch_bounds__(256, 2) void ssim_main(const float* __restrict__ X,
                                                    const float* __restrict__ Y,
                                                    double* __restrict__ partial)
{
    __shared__ float wsum[4];

    const int t     = threadIdx.x;
    const int lane  = t & 63;
    const int wid   = t >> 6;                    // wave in block: 0..3
    const int gw    = blockIdx.x * 4 + wid;      // global wave id: 0..2111
    const int img   = gw / NSTRIP;
    const int strip = gw - img * NSTRIP;
    const int r0    = strip * RSTRIP;            // first output row of strip
    const int c0    = lane * 8;                  // this lane's 8 columns

    const float* xb = X + (size_t)img * (W * HH) + c0;
    const float* yb = Y + (size_t)img * (W * HH) + c0;

    // vertical running sums over the 7-row window, per owned column:
    // V[0]=sum x, V[1]=sum y, V[2]=sum x^2, V[3]=sum y^2, V[4]=sum x*y
    float V[5][8];
#pragma unroll
    for (int q = 0; q < 5; q++)
#pragma unroll
        for (int k = 0; k < 8; k++) V[q][k] = 0.0f;

    // warm-up: rows r0 .. r0+5
#pragma unroll
    for (int r = 0; r < 6; r++) {
        float xs[8], ys[8];
        load8(xb + (size_t)(r0 + r) * W, xs);
        load8(yb + (size_t)(r0 + r) * W, ys);
#pragma unroll
        for (int k = 0; k < 8; k++) {
            V[0][k] += xs[k];
            V[1][k] += ys[k];
            V[2][k] = fmaf(xs[k], xs[k], V[2][k]);
            V[3][k] = fmaf(ys[k], ys[k], V[3][k]);
            V[4][k] = fmaf(xs[k], ys[k], V[4][k]);
        }
    }

    // first bottom row of the window
    float xn[8], yn[8];
    load8(xb + (size_t)(r0 + 6) * W, xn);
    load8(yb + (size_t)(r0 + 6) * W, yn);

    float sacc = 0.0f;

#pragma unroll 1
    for (int j = 0; j < RSTRIP; j++) {
        // add bottom row (r0 + j + 6)
#pragma unroll
        for (int k = 0; k < 8; k++) {
            V[0][k] += xn[k];
            V[1][k] += yn[k];
            V[2][k] = fmaf(xn[k], xn[k], V[2][k]);
            V[3][k] = fmaf(yn[k], yn[k], V[3][k]);
            V[4][k] = fmaf(xn[k], yn[k], V[4][k]);
        }

        // prefetch: top row (to subtract) + next bottom row — latency hides
        // under the horizontal/SSIM compute below.
        float xo[8], yo[8], x2[8], y2[8];
        load8(xb + (size_t)(r0 + j) * W, xo);
        load8(yb + (size_t)(r0 + j) * W, yo);
        int rn = r0 + j + 7; if (rn > HH - 1) rn = HH - 1;   // clamped; unused on last iter
        load8(xb + (size_t)rn * W, x2);
        load8(yb + (size_t)rn * W, y2);

        // horizontal 7-sums: in-lane prefix + 6 halo prefix values from lane+1.
        // Output col c0+k covers cols c0+k .. c0+k+6.
        float Hh[5][8];
#pragma unroll
        for (int q = 0; q < 5; q++) {
            float P[8];
            P[0] = V[q][0];
#pragma unroll
            for (int k = 1; k < 8; k++) P[k] = P[k - 1] + V[q][k];
            const float Pn0 = __shfl_down(P[0], 1);
            const float Pn1 = __shfl_down(P[1], 1);
            const float Pn2 = __shfl_down(P[2], 1);
            const float Pn3 = __shfl_down(P[3], 1);
            const float Pn4 = __shfl_down(P[4], 1);
            const float Pn5 = __shfl_down(P[5], 1);
            const float T = P[7];
            Hh[q][0] = P[6];                    // cols 0..6 (local)
            Hh[q][1] = T - P[0];                // cols 1..7 (local)
            Hh[q][2] = (T - P[1]) + Pn0;        // cols 2..7 + neighbor 0
            Hh[q][3] = (T - P[2]) + Pn1;
            Hh[q][4] = (T - P[3]) + Pn2;
            Hh[q][5] = (T - P[4]) + Pn3;
            Hh[q][6] = (T - P[5]) + Pn4;
            Hh[q][7] = (T - P[6]) + Pn5;        // col 7 + neighbor 0..5
        }

        // SSIM per output pixel (lane 63's k>=2 use garbage halo -> masked)
#pragma unroll
        for (int k = 0; k < 8; k++) {
            float ux  = Hh[0][k] * INV49;
            float uy  = Hh[1][k] * INV49;
            float uxx = Hh[2][k] * INV49;
            float uyy = Hh[3][k] * INV49;
            float uxy = Hh[4][k] * INV49;
            float uxuy = ux * uy;
            float a1 = fmaf(2.0f, uxuy, C1f);                       // 2 ux uy + C1
            float b1 = fmaf(ux, ux, fmaf(uy, uy, C1f));             // ux^2+uy^2+C1
            float vxy = COVN * (uxy - uxuy);
            float a2 = fmaf(2.0f, vxy, C2f);                        // 2 vxy + C2
            float vs  = COVN * ((uxx - ux * ux) + (uyy - uy * uy)); // vx+vy
            float b2 = vs + C2f;
            float S = (a1 * a2) / (b1 * b2);
            if (c0 + k < OW) sacc += S;
        }

        // subtract top row (r0 + j)
#pragma unroll
        for (int k = 0; k < 8; k++) {
            V[0][k] -= xo[k];
            V[1][k] -= yo[k];
            V[2][k] = fmaf(-xo[k], xo[k], V[2][k]);
            V[3][k] = fmaf(-yo[k], yo[k], V[3][k]);
            V[4][k] = fmaf(-xo[k], yo[k], V[4][k]);
        }
#pragma unroll
        for (int k = 0; k < 8; k++) { xn[k] = x2[k]; yn[k] = y2[k]; }
    }

    // reduction: wave shuffle -> LDS -> one partial per block (no atomics)
#pragma unroll
    for (int off = 32; off > 0; off >>= 1)
        sacc += __shfl_down(sacc, off);
    if (lane == 0) wsum[wid] = sacc;
    __syncthreads();
    if (t == 0)
        partial[blockIdx.x] = (double)((wsum[0] + wsum[1]) + (wsum[2] + wsum[3]));
}

__global__ void ssim_finalize(const double* __restrict__ partial, float* __restrict__ out)
{
    __shared__ double ws[4];
    const int t = threadIdx.x;               // 256 threads
    double s = 0.0;
    for (int i = t; i < BLOCKS; i += 256) s += partial[i];
#pragma unroll
    for (int off = 32; off > 0; off >>= 1)
        s += __shfl_down(s, off);
    if ((t & 63) == 0) ws[t >> 6] = s;
    __syncthreads();
    if (t == 0) out[0] = (float)(((ws[0] + ws[1]) + (ws[2] + ws[3])) / NPIX);
}

extern "C" void kernel_launch(void* const* d_in, const int* in_sizes, int n_in,
                              void* d_out, int out_size, void* d_ws, size_t ws_size,
                              hipStream_t stream)
{
    const float* X = (const float*)d_in[0];   // input_tensor (32,3,512,512) fp32
    const float* Y = (const float*)d_in[1];   // target       (32,3,512,512) fp32
    float* out = (float*)d_out;               // scalar fp32
    double* partial = (double*)d_ws;          // 528 doubles

    ssim_main<<<dim3(BLOCKS), 256, 0, stream>>>(X, Y, partial);
    ssim_finalize<<<1, 256, 0, stream>>>(partial, out);
}

// Round 2
// 253.018 us; speedup vs baseline: 1.0110x; 1.0110x over previous
//
#include <hip/hip_runtime.h>

// SSIM (win=7, valid) fused single-pass kernel for (32,3,512,512) fp32 inputs.
// 96 planes of 512x512 -> mean over 96x506x506 S map.
//
// R4: occupancy push + VALU diet.
//   - 46 strips x 11 rows (was 22 x 23): 4416 waves (~17 waves/CU nominal,
//     was 8.25). Latency-bound kernel (R3 counters: VALUBusy 26%, occupancy
//     17%, LLC-fed iteration same speed as HBM-fed) -> more waves/SIMD.
//     Extra row-halo refetch (1.26x -> 1.55x) is absorbed by Infinity Cache.
//   - SSIM algebra on raw 7x7 sums: the 49^2 normalization cancels between
//     numerator and denominator, so C1/C2 are pre-scaled by 49^2 and the five
//     INV49 multiplies disappear. Division replaced by v_rcp + 1 Newton step.
//   - Still zero barriers in the hot loop: lane owns 8 contiguous cols,
//     horizontal 7-sum via in-lane prefix + 6 __shfl_down halo values.

namespace {
constexpr int W       = 512;
constexpr int HH      = 512;
constexpr int NIMG    = 96;
constexpr int OW      = 506;
constexpr int RSTRIP  = 11;               // 46 strips * 11 rows = 506 output rows
constexpr int NSTRIP  = 46;
constexpr int WAVES   = NIMG * NSTRIP;    // 4416
constexpr int BLOCKS  = WAVES / 4;        // 1104 blocks x 4 waves
constexpr float C1s   = 0.2401f;          // C1 * 49^2
constexpr float C2s   = 2.1609f;          // C2 * 49^2
constexpr float COVN  = 49.0f / 48.0f;    // NP/(NP-1)
constexpr double NPIX = 96.0 * 506.0 * 506.0;   // 24,579,456
}

__device__ __forceinline__ void load8(const float* __restrict__ p, float v[8])
{
    float4 a = *(const float4*)(p);
    float4 b = *(const float4*)(p + 4);
    v[0] = a.x; v[1] = a.y; v[2] = a.z; v[3] = a.w;
    v[4] = b.x; v[5] = b.y; v[6] = b.z; v[7] = b.w;
}

__global__ __launch_bounds__(256, 2) void ssim_main(const float* __restrict__ X,
                                                    const float* __restrict__ Y,
                                                    double* __restrict__ partial)
{
    __shared__ float wsum[4];

    const int t     = threadIdx.x;
    const int lane  = t & 63;
    const int wid   = t >> 6;                    // wave in block: 0..3
    const int gw    = blockIdx.x * 4 + wid;      // global wave id: 0..4415
    const int img   = gw / NSTRIP;
    const int strip = gw - img * NSTRIP;
    const int r0    = strip * RSTRIP;            // first output row of strip
    const int c0    = lane * 8;                  // this lane's 8 columns

    const float* xb = X + (size_t)img * (W * HH) + c0;
    const float* yb = Y + (size_t)img * (W * HH) + c0;

    // vertical running sums over the 7-row window, per owned column:
    // V[0]=sum x, V[1]=sum y, V[2]=sum x^2, V[3]=sum y^2, V[4]=sum x*y
    float V[5][8];
#pragma unroll
    for (int q = 0; q < 5; q++)
#pragma unroll
        for (int k = 0; k < 8; k++) V[q][k] = 0.0f;

    // warm-up: rows r0 .. r0+5
#pragma unroll
    for (int r = 0; r < 6; r++) {
        float xs[8], ys[8];
        load8(xb + (size_t)(r0 + r) * W, xs);
        load8(yb + (size_t)(r0 + r) * W, ys);
#pragma unroll
        for (int k = 0; k < 8; k++) {
            V[0][k] += xs[k];
            V[1][k] += ys[k];
            V[2][k] = fmaf(xs[k], xs[k], V[2][k]);
            V[3][k] = fmaf(ys[k], ys[k], V[3][k]);
            V[4][k] = fmaf(xs[k], ys[k], V[4][k]);
        }
    }

    // first bottom row of the window
    float xn[8], yn[8];
    load8(xb + (size_t)(r0 + 6) * W, xn);
    load8(yb + (size_t)(r0 + 6) * W, yn);

    float sacc = 0.0f;

#pragma unroll 1
    for (int j = 0; j < RSTRIP; j++) {
        // add bottom row (r0 + j + 6)
#pragma unroll
        for (int k = 0; k < 8; k++) {
            V[0][k] += xn[k];
            V[1][k] += yn[k];
            V[2][k] = fmaf(xn[k], xn[k], V[2][k]);
            V[3][k] = fmaf(yn[k], yn[k], V[3][k]);
            V[4][k] = fmaf(xn[k], yn[k], V[4][k]);
        }

        // prefetch: top row (to subtract) + next bottom row — latency hides
        // under the horizontal/SSIM compute below.
        float xo[8], yo[8], x2[8], y2[8];
        load8(xb + (size_t)(r0 + j) * W, xo);
        load8(yb + (size_t)(r0 + j) * W, yo);
        int rn = r0 + j + 7; if (rn > HH - 1) rn = HH - 1;   // clamped; unused on last iter
        load8(xb + (size_t)rn * W, x2);
        load8(yb + (size_t)rn * W, y2);

        // horizontal 7-sums: in-lane prefix + 6 halo prefix values from lane+1.
        // Output col c0+k covers cols c0+k .. c0+k+6. Raw sums (x49), no /49.
        float Hh[5][8];
#pragma unroll
        for (int q = 0; q < 5; q++) {
            float P[8];
            P[0] = V[q][0];
#pragma unroll
            for (int k = 1; k < 8; k++) P[k] = P[k - 1] + V[q][k];
            const float Pn0 = __shfl_down(P[0], 1);
            const float Pn1 = __shfl_down(P[1], 1);
            const float Pn2 = __shfl_down(P[2], 1);
            const float Pn3 = __shfl_down(P[3], 1);
            const float Pn4 = __shfl_down(P[4], 1);
            const float Pn5 = __shfl_down(P[5], 1);
            const float T = P[7];
            Hh[q][0] = P[6];                    // cols 0..6 (local)
            Hh[q][1] = T - P[0];                // cols 1..7 (local)
            Hh[q][2] = (T - P[1]) + Pn0;        // cols 2..7 + neighbor 0
            Hh[q][3] = (T - P[2]) + Pn1;
            Hh[q][4] = (T - P[3]) + Pn2;
            Hh[q][5] = (T - P[4]) + Pn3;
            Hh[q][6] = (T - P[5]) + Pn4;
            Hh[q][7] = (T - P[6]) + Pn5;        // col 7 + neighbor 0..5
        }

        // SSIM per output pixel, on raw 49-sums (normalization cancels):
        //   A=49ux B=49uy P=49uxx Q=49uyy R=49uxy
        //   num = (2AB + C1*49^2) * (2*COVN*(49R - AB) + C2*49^2)
        //   den = (A^2+B^2 + C1*49^2) * (COVN*(49(P+Q) - A^2-B^2) + C2*49^2)
#pragma unroll
        for (int k = 0; k < 8; k++) {
            float A = Hh[0][k], B = Hh[1][k];
            float Pq = Hh[2][k], Qq = Hh[3][k], R = Hh[4][k];
            float AB   = A * B;
            float a1   = fmaf(2.0f, AB, C1s);
            float ab2  = fmaf(A, A, B * B);
            float b1   = ab2 + C1s;
            float tt   = fmaf(49.0f, R, -AB);
            float a2   = fmaf(2.0f * COVN, tt, C2s);
            float pq   = Pq + Qq;
            float t2   = fmaf(49.0f, pq, -ab2);
            float b2   = fmaf(COVN, t2, C2s);
            float num  = a1 * a2;
            float den  = b1 * b2;
            float r    = __builtin_amdgcn_rcpf(den);
            r = r * fmaf(-den, r, 2.0f);        // 1 Newton step -> ~0.5 ulp
            float S = num * r;
            if (c0 + k < OW) sacc += S;
        }

        // subtract top row (r0 + j)
#pragma unroll
        for (int k = 0; k < 8; k++) {
            V[0][k] -= xo[k];
            V[1][k] -= yo[k];
            V[2][k] = fmaf(-xo[k], xo[k], V[2][k]);
            V[3][k] = fmaf(-yo[k], yo[k], V[3][k]);
            V[4][k] = fmaf(-xo[k], yo[k], V[4][k]);
        }
#pragma unroll
        for (int k = 0; k < 8; k++) { xn[k] = x2[k]; yn[k] = y2[k]; }
    }

    // reduction: wave shuffle -> LDS -> one partial per block (no atomics)
#pragma unroll
    for (int off = 32; off > 0; off >>= 1)
        sacc += __shfl_down(sacc, off);
    if (lane == 0) wsum[wid] = sacc;
    __syncthreads();
    if (t == 0)
        partial[blockIdx.x] = (double)((wsum[0] + wsum[1]) + (wsum[2] + wsum[3]));
}

__global__ void ssim_finalize(const double* __restrict__ partial, float* __restrict__ out)
{
    __shared__ double ws[4];
    const int t = threadIdx.x;               // 256 threads
    double s = 0.0;
    for (int i = t; i < BLOCKS; i += 256) s += partial[i];
#pragma unroll
    for (int off = 32; off > 0; off >>= 1)
        s += __shfl_down(s, off);
    if ((t & 63) == 0) ws[t >> 6] = s;
    __syncthreads();
    if (t == 0) out[0] = (float)(((ws[0] + ws[1]) + (ws[2] + ws[3])) / NPIX);
}

extern "C" void kernel_launch(void* const* d_in, const int* in_sizes, int n_in,
                              void* d_out, int out_size, void* d_ws, size_t ws_size,
                              hipStream_t stream)
{
    const float* X = (const float*)d_in[0];   // input_tensor (32,3,512,512) fp32
    const float* Y = (const float*)d_in[1];   // target       (32,3,512,512) fp32
    float* out = (float*)d_out;               // scalar fp32
    double* partial = (double*)d_ws;          // 1104 doubles

    ssim_main<<<dim3(BLOCKS), 256, 0, stream>>>(X, Y, partial);
    ssim_finalize<<<1, 256, 0, stream>>>(partial, out);
}

// Round 3
// 242.886 us; speedup vs baseline: 1.0532x; 1.0417x over previous
//
#include <hip/hip_runtime.h>

// SSIM (win=7, valid) fused single-pass kernel for (32,3,512,512) fp32 inputs.
// 96 planes of 512x512 -> mean over 96x506x506 S map.
//
// R5: HBM locality push. R4 counters showed a ~2.3 TB/s service-rate wall:
// occupancy 2x'd (17->35%) but BW only +18%, VALU/LDS pipes idle, time flat.
// Little's law: ~22 MB in flight / 2.3 TB/s ~ 10 us queue latency. The
// concurrent footprint is a 1/11-density strided sample (strips 22 KB apart,
// scattered across XCDs) -> poor DRAM row-buffer locality, and L2/LLC absorb
// almost none of the 1.53x strip-halo re-reads (FETCH ~= fully amplified).
//   - XCD-chunked block swizzle (1104 blocks = 8 x 138): each XCD owns 12
//     consecutive images -> dense per-XCD streams; halo-sharing adjacent
//     strips co-resident on one XCD (3/4 inside the same block) -> overlap
//     rows served by L1/L2 instead of HBM.
//   - Full 1-ahead prefetch: both next-iteration rows (bottom r0+j+7, top
//     r0+j+1) issued one iteration before use; no same-iter load->use.
//   - Unchanged: wave-autonomous strips (zero barriers in hot loop), lane owns
//     8 contiguous cols, horizontal 7-sum via in-lane prefix + 6 __shfl_down,
//     SSIM on raw 49-sums with rcp+Newton.

namespace {
constexpr int W       = 512;
constexpr int HH      = 512;
constexpr int NIMG    = 96;
constexpr int OW      = 506;
constexpr int RSTRIP  = 11;               // 46 strips * 11 rows = 506 output rows
constexpr int NSTRIP  = 46;
constexpr int WAVES   = NIMG * NSTRIP;    // 4416
constexpr int BLOCKS  = WAVES / 4;        // 1104 blocks x 4 waves
constexpr int NXCD    = 8;
constexpr int CPX     = BLOCKS / NXCD;    // 138 (exact: 1104 % 8 == 0 -> bijective)
constexpr float C1s   = 0.2401f;          // C1 * 49^2
constexpr float C2s   = 2.1609f;          // C2 * 49^2
constexpr float COVN  = 49.0f / 48.0f;    // NP/(NP-1)
constexpr double NPIX = 96.0 * 506.0 * 506.0;   // 24,579,456
}

__device__ __forceinline__ void load8(const float* __restrict__ p, float v[8])
{
    float4 a = *(const float4*)(p);
    float4 b = *(const float4*)(p + 4);
    v[0] = a.x; v[1] = a.y; v[2] = a.z; v[3] = a.w;
    v[4] = b.x; v[5] = b.y; v[6] = b.z; v[7] = b.w;
}

__global__ __launch_bounds__(256, 2) void ssim_main(const float* __restrict__ X,
                                                    const float* __restrict__ Y,
                                                    double* __restrict__ partial)
{
    __shared__ float wsum[4];

    const int t    = threadIdx.x;
    const int lane = t & 63;
    const int wid  = t >> 6;                      // wave in block: 0..3

    // XCD-chunked swizzle: consecutive logical blocks land on one XCD.
    const int bid  = blockIdx.x;
    const int swz  = (bid % NXCD) * CPX + bid / NXCD;

    const int gw    = swz * 4 + wid;              // global wave id: 0..4415
    const int img   = gw / NSTRIP;
    const int strip = gw - img * NSTRIP;
    const int r0    = strip * RSTRIP;             // first output row of strip
    const int c0    = lane * 8;                   // this lane's 8 columns

    const float* xb = X + (size_t)img * (W * HH) + c0;
    const float* yb = Y + (size_t)img * (W * HH) + c0;

    // vertical running sums over the 7-row window, per owned column:
    // V[0]=sum x, V[1]=sum y, V[2]=sum x^2, V[3]=sum y^2, V[4]=sum x*y
    float V[5][8];
#pragma unroll
    for (int q = 0; q < 5; q++)
#pragma unroll
        for (int k = 0; k < 8; k++) V[q][k] = 0.0f;

    // top row of the first window (kept for the j=0 subtract)
    float xo[8], yo[8];

    // warm-up: rows r0 .. r0+5
#pragma unroll
    for (int r = 0; r < 6; r++) {
        float xs[8], ys[8];
        load8(xb + (size_t)(r0 + r) * W, xs);
        load8(yb + (size_t)(r0 + r) * W, ys);
#pragma unroll
        for (int k = 0; k < 8; k++) {
            V[0][k] += xs[k];
            V[1][k] += ys[k];
            V[2][k] = fmaf(xs[k], xs[k], V[2][k]);
            V[3][k] = fmaf(ys[k], ys[k], V[3][k]);
            V[4][k] = fmaf(xs[k], ys[k], V[4][k]);
        }
        if (r == 0) {
#pragma unroll
            for (int k = 0; k < 8; k++) { xo[k] = xs[k]; yo[k] = ys[k]; }
        }
    }

    // bottom row of the first window
    float xn[8], yn[8];
    load8(xb + (size_t)(r0 + 6) * W, xn);
    load8(yb + (size_t)(r0 + 6) * W, yn);

    float sacc = 0.0f;

#pragma unroll 1
    for (int j = 0; j < RSTRIP; j++) {
        // add bottom row (r0 + j + 6), already in registers
#pragma unroll
        for (int k = 0; k < 8; k++) {
            V[0][k] += xn[k];
            V[1][k] += yn[k];
            V[2][k] = fmaf(xn[k], xn[k], V[2][k]);
            V[3][k] = fmaf(yn[k], yn[k], V[3][k]);
            V[4][k] = fmaf(xn[k], yn[k], V[4][k]);
        }

        // prefetch rows for iteration j+1: bottom r0+j+7, top r0+j+1.
        // Full iteration of compute between issue and use.
        float xnp[8], ynp[8], xop[8], yop[8];
        int rb = r0 + j + 7; if (rb > HH - 1) rb = HH - 1;   // clamped; unused on last iter
        load8(xb + (size_t)rb * W, xnp);
        load8(yb + (size_t)rb * W, ynp);
        load8(xb + (size_t)(r0 + j + 1) * W, xop);
        load8(yb + (size_t)(r0 + j + 1) * W, yop);

        // horizontal 7-sums: in-lane prefix + 6 halo prefix values from lane+1.
        // Output col c0+k covers cols c0+k .. c0+k+6. Raw sums (x49), no /49.
        float Hh[5][8];
#pragma unroll
        for (int q = 0; q < 5; q++) {
            float P[8];
            P[0] = V[q][0];
#pragma unroll
            for (int k = 1; k < 8; k++) P[k] = P[k - 1] + V[q][k];
            const float Pn0 = __shfl_down(P[0], 1);
            const float Pn1 = __shfl_down(P[1], 1);
            const float Pn2 = __shfl_down(P[2], 1);
            const float Pn3 = __shfl_down(P[3], 1);
            const float Pn4 = __shfl_down(P[4], 1);
            const float Pn5 = __shfl_down(P[5], 1);
            const float T = P[7];
            Hh[q][0] = P[6];                    // cols 0..6 (local)
            Hh[q][1] = T - P[0];                // cols 1..7 (local)
            Hh[q][2] = (T - P[1]) + Pn0;        // cols 2..7 + neighbor 0
            Hh[q][3] = (T - P[2]) + Pn1;
            Hh[q][4] = (T - P[3]) + Pn2;
            Hh[q][5] = (T - P[4]) + Pn3;
            Hh[q][6] = (T - P[5]) + Pn4;
            Hh[q][7] = (T - P[6]) + Pn5;        // col 7 + neighbor 0..5
        }

        // SSIM per output pixel, on raw 49-sums (normalization cancels):
        //   A=49ux B=49uy P=49uxx Q=49uyy R=49uxy
        //   num = (2AB + C1*49^2) * (2*COVN*(49R - AB) + C2*49^2)
        //   den = (A^2+B^2 + C1*49^2) * (COVN*(49(P+Q) - A^2-B^2) + C2*49^2)
#pragma unroll
        for (int k = 0; k < 8; k++) {
            float A = Hh[0][k], B = Hh[1][k];
            float Pq = Hh[2][k], Qq = Hh[3][k], R = Hh[4][k];
            float AB   = A * B;
            float a1   = fmaf(2.0f, AB, C1s);
            float ab2  = fmaf(A, A, B * B);
            float b1   = ab2 + C1s;
            float tt   = fmaf(49.0f, R, -AB);
            float a2   = fmaf(2.0f * COVN, tt, C2s);
            float pq   = Pq + Qq;
            float t2   = fmaf(49.0f, pq, -ab2);
            float b2   = fmaf(COVN, t2, C2s);
            float num  = a1 * a2;
            float den  = b1 * b2;
            float r    = __builtin_amdgcn_rcpf(den);
            r = r * fmaf(-den, r, 2.0f);        // 1 Newton step -> ~0.5 ulp
            float S = num * r;
            if (c0 + k < OW) sacc += S;
        }

        // subtract top row (r0 + j), already in registers
#pragma unroll
        for (int k = 0; k < 8; k++) {
            V[0][k] -= xo[k];
            V[1][k] -= yo[k];
            V[2][k] = fmaf(-xo[k], xo[k], V[2][k]);
            V[3][k] = fmaf(-yo[k], yo[k], V[3][k]);
            V[4][k] = fmaf(-xo[k], yo[k], V[4][k]);
        }

        // rotate prefetched rows into place
#pragma unroll
        for (int k = 0; k < 8; k++) {
            xn[k] = xnp[k]; yn[k] = ynp[k];
            xo[k] = xop[k]; yo[k] = yop[k];
        }
    }

    // reduction: wave shuffle -> LDS -> one partial per block (no atomics)
#pragma unroll
    for (int off = 32; off > 0; off >>= 1)
        sacc += __shfl_down(sacc, off);
    if (lane == 0) wsum[wid] = sacc;
    __syncthreads();
    if (t == 0)
        partial[blockIdx.x] = (double)((wsum[0] + wsum[1]) + (wsum[2] + wsum[3]));
}

__global__ void ssim_finalize(const double* __restrict__ partial, float* __restrict__ out)
{
    __shared__ double ws[4];
    const int t = threadIdx.x;               // 256 threads
    double s = 0.0;
    for (int i = t; i < BLOCKS; i += 256) s += partial[i];
#pragma unroll
    for (int off = 32; off > 0; off >>= 1)
        s += __shfl_down(s, off);
    if ((t & 63) == 0) ws[t >> 6] = s;
    __syncthreads();
    if (t == 0) out[0] = (float)(((ws[0] + ws[1]) + (ws[2] + ws[3])) / NPIX);
}

extern "C" void kernel_launch(void* const* d_in, const int* in_sizes, int n_in,
                              void* d_out, int out_size, void* d_ws, size_t ws_size,
                              hipStream_t stream)
{
    const float* X = (const float*)d_in[0];   // input_tensor (32,3,512,512) fp32
    const float* Y = (const float*)d_in[1];   // target       (32,3,512,512) fp32
    float* out = (float*)d_out;               // scalar fp32
    double* partial = (double*)d_ws;          // 1104 doubles

    ssim_main<<<dim3(BLOCKS), 256, 0, stream>>>(X, Y, partial);
    ssim_finalize<<<1, 256, 0, stream>>>(partial, out);
}

// Round 4
// 236.449 us; speedup vs baseline: 1.0818x; 1.0272x over previous
//
#include <hip/hip_runtime.h>

// SSIM (win=7, valid) fused single-pass kernel for (32,3,512,512) fp32 inputs.
// 96 planes of 512x512 -> mean over 96x506x506 S map.
//
// R6: force a real 2-row-ahead load pipeline. R5's VGPR=72 proved the
// compiler sank the "1-ahead" prefetch loads back to their uses (72 = V:40 +
// 4 row bufs:32, zero left for prefetch) -> effective MLP ~8 loads/wave and
// BW stuck at 2.5 TB/s while VALU 22% / LDS 0% / occupancy idle.
//   - Ring buffers B0/B1 (bottom rows) + T0/T1 (top re-read rows), indexed
//     at compile time (2-unrolled loop + peeled tail): body(j) consumes its
//     buffer then immediately reissues it for row j+8 (bottom) / j+2 (top),
//     pinned with sched_barrier(0) so the scheduler can't sink the issue.
//     Steady state: 16 dwordx4 in flight/wave, issue->use ~2 row-computes.
//   - Warmup reuses ring rows r0,r0+1; ring loads issued first for start MLP.
//   - Kept from R5: XCD-chunked block swizzle (1104 = 8*138, bijective),
//     wave-autonomous strips (zero barriers), lane owns 8 contiguous cols,
//     horizontal 7-sum via in-lane prefix + 6 __shfl_down, SSIM on raw
//     49-sums with rcp+Newton (absmax was 0.0).

namespace {
constexpr int W       = 512;
constexpr int HH      = 512;
constexpr int NIMG    = 96;
constexpr int OW      = 506;
constexpr int RSTRIP  = 11;               // 46 strips * 11 rows = 506 output rows
constexpr int NSTRIP  = 46;
constexpr int WAVES   = NIMG * NSTRIP;    // 4416
constexpr int BLOCKS  = WAVES / 4;        // 1104 blocks x 4 waves
constexpr int NXCD    = 8;
constexpr int CPX     = BLOCKS / NXCD;    // 138 (1104 % 8 == 0 -> bijective)
constexpr float C1s   = 0.2401f;          // C1 * 49^2
constexpr float C2s   = 2.1609f;          // C2 * 49^2
constexpr float COVN  = 49.0f / 48.0f;    // NP/(NP-1)
constexpr double NPIX = 96.0 * 506.0 * 506.0;   // 24,579,456
}

__device__ __forceinline__ void load8(const float* __restrict__ p, float (&v)[8])
{
    float4 a = *(const float4*)(p);
    float4 b = *(const float4*)(p + 4);
    v[0] = a.x; v[1] = a.y; v[2] = a.z; v[3] = a.w;
    v[4] = b.x; v[5] = b.y; v[6] = b.z; v[7] = b.w;
}

__device__ __forceinline__ void vadd(float (&V)[5][8], const float (&x)[8], const float (&y)[8])
{
#pragma unroll
    for (int k = 0; k < 8; k++) {
        V[0][k] += x[k];
        V[1][k] += y[k];
        V[2][k] = fmaf(x[k], x[k], V[2][k]);
        V[3][k] = fmaf(y[k], y[k], V[3][k]);
        V[4][k] = fmaf(x[k], y[k], V[4][k]);
    }
}

__device__ __forceinline__ void vsub(float (&V)[5][8], const float (&x)[8], const float (&y)[8])
{
#pragma unroll
    for (int k = 0; k < 8; k++) {
        V[0][k] -= x[k];
        V[1][k] -= y[k];
        V[2][k] = fmaf(-x[k], x[k], V[2][k]);
        V[3][k] = fmaf(-y[k], y[k], V[3][k]);
        V[4][k] = fmaf(-x[k], y[k], V[4][k]);
    }
}

// horizontal 7-sums (in-lane prefix + 6 halo values from lane+1) and the
// SSIM evaluation on raw 49-sums. Output col c0+k covers cols c0+k..c0+k+6.
__device__ __forceinline__ void hssim(const float (&V)[5][8], float& sacc, int c0)
{
    float Hh[5][8];
#pragma unroll
    for (int q = 0; q < 5; q++) {
        float P[8];
        P[0] = V[q][0];
#pragma unroll
        for (int k = 1; k < 8; k++) P[k] = P[k - 1] + V[q][k];
        const float Pn0 = __shfl_down(P[0], 1);
        const float Pn1 = __shfl_down(P[1], 1);
        const float Pn2 = __shfl_down(P[2], 1);
        const float Pn3 = __shfl_down(P[3], 1);
        const float Pn4 = __shfl_down(P[4], 1);
        const float Pn5 = __shfl_down(P[5], 1);
        const float T = P[7];
        Hh[q][0] = P[6];
        Hh[q][1] = T - P[0];
        Hh[q][2] = (T - P[1]) + Pn0;
        Hh[q][3] = (T - P[2]) + Pn1;
        Hh[q][4] = (T - P[3]) + Pn2;
        Hh[q][5] = (T - P[4]) + Pn3;
        Hh[q][6] = (T - P[5]) + Pn4;
        Hh[q][7] = (T - P[6]) + Pn5;
    }

    //   A=49ux B=49uy P=49uxx Q=49uyy R=49uxy
    //   num = (2AB + C1*49^2) * (2*COVN*(49R - AB) + C2*49^2)
    //   den = (A^2+B^2 + C1*49^2) * (COVN*(49(P+Q) - A^2-B^2) + C2*49^2)
#pragma unroll
    for (int k = 0; k < 8; k++) {
        float A = Hh[0][k], B = Hh[1][k];
        float Pq = Hh[2][k], Qq = Hh[3][k], R = Hh[4][k];
        float AB  = A * B;
        float a1  = fmaf(2.0f, AB, C1s);
        float ab2 = fmaf(A, A, B * B);
        float b1  = ab2 + C1s;
        float tt  = fmaf(49.0f, R, -AB);
        float a2  = fmaf(2.0f * COVN, tt, C2s);
        float pq  = Pq + Qq;
        float t2  = fmaf(49.0f, pq, -ab2);
        float b2  = fmaf(COVN, t2, C2s);
        float num = a1 * a2;
        float den = b1 * b2;
        float r   = __builtin_amdgcn_rcpf(den);
        r = r * fmaf(-den, r, 2.0f);        // 1 Newton step -> ~0.5 ulp
        float S = num * r;
        if (c0 + k < OW) sacc += S;
    }
}

// One output row jj. On entry: V = rows jj..jj+5, (Bx,By) = row jj+6,
// (Tx,Ty) = row jj. PREB: reissue B := row jj+8 (consumed at body jj+2).
// PRET: reissue T := row jj+2 (consumed at body jj+2).
template<bool PREB, bool PRET>
__device__ __forceinline__ void ssim_row(int jj, int r0,
        const float* __restrict__ xb, const float* __restrict__ yb,
        float (&V)[5][8],
        float (&Bx)[8], float (&By)[8],
        float (&Tx)[8], float (&Ty)[8],
        float& sacc, int c0)
{
    vadd(V, Bx, By);                         // window complete: rows jj..jj+6
    if (PREB) {
        int rb = r0 + jj + 8; if (rb > HH - 1) rb = HH - 1;
        load8(xb + (size_t)rb * W, Bx);
        load8(yb + (size_t)rb * W, By);
        __builtin_amdgcn_sched_barrier(0);   // pin issue point: no sinking
    }
    hssim(V, sacc, c0);
    vsub(V, Tx, Ty);                         // drop row jj -> rows jj+1..jj+6
    if (PRET) {
        int rt = r0 + jj + 2; if (rt > HH - 1) rt = HH - 1;
        load8(xb + (size_t)rt * W, Tx);
        load8(yb + (size_t)rt * W, Ty);
        __builtin_amdgcn_sched_barrier(0);
    }
}

__global__ __launch_bounds__(256, 2) void ssim_main(const float* __restrict__ X,
                                                    const float* __restrict__ Y,
                                                    double* __restrict__ partial)
{
    __shared__ float wsum[4];

    const int t    = threadIdx.x;
    const int lane = t & 63;
    const int wid  = t >> 6;                      // wave in block: 0..3

    // XCD-chunked swizzle: consecutive logical blocks land on one XCD.
    const int bid  = blockIdx.x;
    const int swz  = (bid % NXCD) * CPX + bid / NXCD;

    const int gw    = swz * 4 + wid;              // global wave id: 0..4415
    const int img   = gw / NSTRIP;
    const int strip = gw - img * NSTRIP;
    const int r0    = strip * RSTRIP;             // first output row of strip
    const int c0    = lane * 8;                   // this lane's 8 columns

    const float* xb = X + (size_t)img * (W * HH) + c0;
    const float* yb = Y + (size_t)img * (W * HH) + c0;

    // ring buffers: B = bottom rows (jj+6), T = top re-read rows (jj)
    float B0x[8], B0y[8], B1x[8], B1y[8];
    float T0x[8], T0y[8], T1x[8], T1y[8];

    // issue ring fills first (max startup MLP):
    load8(xb + (size_t)(r0 + 6) * W, B0x); load8(yb + (size_t)(r0 + 6) * W, B0y);
    load8(xb + (size_t)(r0 + 7) * W, B1x); load8(yb + (size_t)(r0 + 7) * W, B1y);
    load8(xb + (size_t)(r0 + 0) * W, T0x); load8(yb + (size_t)(r0 + 0) * W, T0y);
    load8(xb + (size_t)(r0 + 1) * W, T1x); load8(yb + (size_t)(r0 + 1) * W, T1y);

    // vertical running sums V[0]=x V[1]=y V[2]=x^2 V[3]=y^2 V[4]=xy
    float V[5][8];
#pragma unroll
    for (int q = 0; q < 5; q++)
#pragma unroll
        for (int k = 0; k < 8; k++) V[q][k] = 0.0f;

    // warm-up rows r0..r0+5: rows 0,1 come from the ring (T0/T1 keep their
    // values for the j=0/1 subtract); rows 2..5 through two scratch buffers.
    {
        float wax[8], way[8], wbx[8], wby[8];
        load8(xb + (size_t)(r0 + 2) * W, wax); load8(yb + (size_t)(r0 + 2) * W, way);
        load8(xb + (size_t)(r0 + 3) * W, wbx); load8(yb + (size_t)(r0 + 3) * W, wby);
        vadd(V, T0x, T0y);
        vadd(V, T1x, T1y);
        vadd(V, wax, way);
        load8(xb + (size_t)(r0 + 4) * W, wax); load8(yb + (size_t)(r0 + 4) * W, way);
        vadd(V, wbx, wby);
        load8(xb + (size_t)(r0 + 5) * W, wbx); load8(yb + (size_t)(r0 + 5) * W, wby);
        vadd(V, wax, way);
        vadd(V, wbx, wby);
    }

    float sacc = 0.0f;

    // rows 0..7: 2-unrolled ring; each body reissues its buffers for +2 rows.
#pragma unroll 1
    for (int j = 0; j < 8; j += 2) {
        ssim_row<true,  true >(j,     r0, xb, yb, V, B0x, B0y, T0x, T0y, sacc, c0);
        ssim_row<true,  true >(j + 1, r0, xb, yb, V, B1x, B1y, T1x, T1y, sacc, c0);
    }
    // peeled tail: row 8 prefetches row 16 (B0) and row 10 (T0) for row 10;
    // rows 9 and 10 issue nothing (their prefetches would be dead).
    ssim_row<true,  true >( 8, r0, xb, yb, V, B0x, B0y, T0x, T0y, sacc, c0);
    ssim_row<false, false>( 9, r0, xb, yb, V, B1x, B1y, T1x, T1y, sacc, c0);
    ssim_row<false, false>(10, r0, xb, yb, V, B0x, B0y, T0x, T0y, sacc, c0);

    // reduction: wave shuffle -> LDS -> one partial per block (no atomics)
#pragma unroll
    for (int off = 32; off > 0; off >>= 1)
        sacc += __shfl_down(sacc, off);
    if (lane == 0) wsum[wid] = sacc;
    __syncthreads();
    if (t == 0)
        partial[blockIdx.x] = (double)((wsum[0] + wsum[1]) + (wsum[2] + wsum[3]));
}

__global__ void ssim_finalize(const double* __restrict__ partial, float* __restrict__ out)
{
    __shared__ double ws[4];
    const int t = threadIdx.x;               // 256 threads
    double s = 0.0;
    for (int i = t; i < BLOCKS; i += 256) s += partial[i];
#pragma unroll
    for (int off = 32; off > 0; off >>= 1)
        s += __shfl_down(s, off);
    if ((t & 63) == 0) ws[t >> 6] = s;
    __syncthreads();
    if (t == 0) out[0] = (float)(((ws[0] + ws[1]) + (ws[2] + ws[3])) / NPIX);
}

extern "C" void kernel_launch(void* const* d_in, const int* in_sizes, int n_in,
                              void* d_out, int out_size, void* d_ws, size_t ws_size,
                              hipStream_t stream)
{
    const float* X = (const float*)d_in[0];   // input_tensor (32,3,512,512) fp32
    const float* Y = (const float*)d_in[1];   // target       (32,3,512,512) fp32
    float* out = (float*)d_out;               // scalar fp32
    double* partial = (double*)d_ws;          // 1104 doubles

    ssim_main<<<dim3(BLOCKS), 256, 0, stream>>>(X, Y, partial);
    ssim_finalize<<<1, 256, 0, stream>>>(partial, out);
}